// Round 1
// baseline (604.525 us; speedup 1.0000x reference)
//
#include <hip/hip_runtime.h>
#include <hip/hip_bf16.h>

#define NTOKEN 150000
#define NINP   64
#define NHID   128
#define NEDGE  2400000
#define NPOS   (64*200)

// word (4-byte) offsets into workspace
#define O_DINV      0              // f32 [150000]
#define O_COUNTS    150016         // i32 [150000]
#define O_ROWSTART  300032         // i32 [150001]
#define O_CURSOR    450048         // i32 [150000]
#define O_BSUMS     600064         // i32 [256]
#define O_M         600320         // f32 [4096]   (W1@W2)
#define O_CVEC      604416         // f32 [64]     (b1@W2)
#define O_SORTED    604480         // i32 [2400000]
#define O_Z1        3004480        // f32 [150000*64]
// total ~50.5 MB

__global__ void k_count(const int* __restrict__ dst, int* __restrict__ counts) {
    int e = blockIdx.x * blockDim.x + threadIdx.x;
    if (e < NEDGE) atomicAdd(&counts[dst[e]], 1);
}

__global__ void k_scan_part(const int* __restrict__ counts, int* __restrict__ rowStart,
                            int* __restrict__ bsums) {
    __shared__ int sd[256];
    int tid = threadIdx.x;
    int base = blockIdx.x * 1024 + tid * 4;
    int c0 = (base + 0 < NTOKEN) ? counts[base + 0] : 0;
    int c1 = (base + 1 < NTOKEN) ? counts[base + 1] : 0;
    int c2 = (base + 2 < NTOKEN) ? counts[base + 2] : 0;
    int c3 = (base + 3 < NTOKEN) ? counts[base + 3] : 0;
    int tsum = c0 + c1 + c2 + c3;
    sd[tid] = tsum;
    __syncthreads();
    for (int off = 1; off < 256; off <<= 1) {
        int v = (tid >= off) ? sd[tid - off] : 0;
        __syncthreads();
        sd[tid] += v;
        __syncthreads();
    }
    int excl = sd[tid] - tsum;           // exclusive prefix of thread sums
    if (tid == 255) bsums[blockIdx.x] = sd[255];
    if (base + 0 < NTOKEN) rowStart[base + 0] = excl;
    if (base + 1 < NTOKEN) rowStart[base + 1] = excl + c0;
    if (base + 2 < NTOKEN) rowStart[base + 2] = excl + c0 + c1;
    if (base + 3 < NTOKEN) rowStart[base + 3] = excl + c0 + c1 + c2;
}

__global__ void k_scan_bsums(int* __restrict__ bsums, int nb) {
    __shared__ int sd[256];
    int tid = threadIdx.x;
    int v = (tid < nb) ? bsums[tid] : 0;
    sd[tid] = v;
    __syncthreads();
    for (int off = 1; off < 256; off <<= 1) {
        int t = (tid >= off) ? sd[tid - off] : 0;
        __syncthreads();
        sd[tid] += t;
        __syncthreads();
    }
    if (tid < nb) bsums[tid] = sd[tid] - v;  // exclusive
}

__global__ void k_scan_add(int* __restrict__ rowStart, int* __restrict__ cursor,
                           const int* __restrict__ bsums) {
    int tid = threadIdx.x;
    int base = blockIdx.x * 1024 + tid * 4;
    int add = bsums[blockIdx.x];
    for (int r = 0; r < 4; r++) {
        int i = base + r;
        if (i < NTOKEN) { int s = rowStart[i] + add; rowStart[i] = s; cursor[i] = s; }
    }
    if (blockIdx.x == 0 && tid == 0) rowStart[NTOKEN] = NEDGE;
}

__global__ void k_dinv(const int* __restrict__ counts, float* __restrict__ dinv) {
    int v = blockIdx.x * blockDim.x + threadIdx.x;
    if (v < NTOKEN) dinv[v] = rsqrtf((float)counts[v] + 1.0f);
}

__global__ void k_scatter(const int* __restrict__ ei, int* __restrict__ cursor,
                          int* __restrict__ sortedSrc) {
    int e = blockIdx.x * blockDim.x + threadIdx.x;
    if (e < NEDGE) {
        int s = ei[e];
        int d = ei[NEDGE + e];
        int pos = atomicAdd(&cursor[d], 1);
        sortedSrc[pos] = s;
    }
}

// M = W1 @ W2  (64x64, K=128);  cvec = b1 @ W2  (64)
__global__ void k_smallmat(const float* __restrict__ W1, const float* __restrict__ b1,
                           const float* __restrict__ W2,
                           float* __restrict__ M, float* __restrict__ cvec) {
    int tid = threadIdx.x;
    for (int o = tid; o < 64 * 64; o += 256) {
        int i = o >> 6, j = o & 63;
        float s = 0.f;
        for (int k = 0; k < 128; k++) s += W1[i * 128 + k] * W2[k * 64 + j];
        M[o] = s;
    }
    if (tid < 64) {
        float s = 0.f;
        for (int k = 0; k < 128; k++) s += b1[k] * W2[k * 64 + tid];
        cvec[tid] = s;
    }
}

// Z1 = Ahat @ X ; one wave per dst node, lane = feature
__global__ void k_agg1(const float* __restrict__ X, const float* __restrict__ dinv,
                       const int* __restrict__ rowStart, const int* __restrict__ sortedSrc,
                       float* __restrict__ Z1) {
    int wave = threadIdx.x >> 6;
    int lane = threadIdx.x & 63;
    int v = blockIdx.x * 4 + wave;
    if (v >= NTOKEN) return;
    int e0 = rowStart[v], e1 = rowStart[v + 1];
    float sum = 0.f;
    for (int e = e0; e < e1; e++) {
        int u = sortedSrc[e];
        float du = dinv[u];
        sum += du * X[(size_t)u * 64 + lane];
    }
    float dv = dinv[v];
    Z1[(size_t)v * 64 + lane] = dv * sum + dv * dv * X[(size_t)v * 64 + lane];
}

// out[p] = (Ahat @ Z1)[v] @ M + s[v]*cvec + b2 ; one wave per output position
__global__ void k_out(const int* __restrict__ inp, const float* __restrict__ Z1,
                      const float* __restrict__ dinv, const int* __restrict__ rowStart,
                      const int* __restrict__ sortedSrc, const float* __restrict__ M,
                      const float* __restrict__ cvec, const float* __restrict__ b2,
                      float* __restrict__ out) {
    int p = blockIdx.x;
    int lane = threadIdx.x;
    int v = inp[p];
    int e0 = rowStart[v], e1 = rowStart[v + 1];
    float sum = 0.f, ss = 0.f;
    for (int e = e0; e < e1; e++) {
        int u = sortedSrc[e];
        float du = dinv[u];
        sum += du * Z1[(size_t)u * 64 + lane];
        ss  += du;
    }
    float dv = dinv[v];
    float z2 = dv * sum + dv * dv * Z1[(size_t)v * 64 + lane];
    float s  = dv * ss + dv * dv;
    float acc = s * cvec[lane] + b2[lane];
    for (int k = 0; k < 64; k++) {
        float zk = __shfl(z2, k, 64);
        acc += zk * M[k * 64 + lane];
    }
    out[(size_t)p * 64 + lane] = acc;
}

extern "C" void kernel_launch(void* const* d_in, const int* in_sizes, int n_in,
                              void* d_out, int out_size, void* d_ws, size_t ws_size,
                              hipStream_t stream) {
    const float* emb = (const float*)d_in[0];
    const float* W1  = (const float*)d_in[1];
    const float* b1  = (const float*)d_in[2];
    const float* W2  = (const float*)d_in[3];
    const float* b2  = (const float*)d_in[4];
    const int*   inp = (const int*)d_in[5];
    // d_in[6] = input_timestamp (unused by the reference)
    const int*   ei  = (const int*)d_in[7];
    float* out = (float*)d_out;

    float* ws       = (float*)d_ws;
    float* dinv     = ws + O_DINV;
    int*   counts   = (int*)ws + O_COUNTS;
    int*   rowStart = (int*)ws + O_ROWSTART;
    int*   cursor   = (int*)ws + O_CURSOR;
    int*   bsums    = (int*)ws + O_BSUMS;
    float* M        = ws + O_M;
    float* cvec     = ws + O_CVEC;
    int*   sortedSrc= (int*)ws + O_SORTED;
    float* Z1       = ws + O_Z1;

    hipMemsetAsync(counts, 0, NTOKEN * sizeof(int), stream);

    k_count    <<<(NEDGE + 255) / 256, 256, 0, stream>>>(ei + NEDGE, counts);
    k_scan_part<<<147, 256, 0, stream>>>(counts, rowStart, bsums);
    k_scan_bsums<<<1, 256, 0, stream>>>(bsums, 147);
    k_scan_add <<<147, 256, 0, stream>>>(rowStart, cursor, bsums);
    k_dinv     <<<(NTOKEN + 255) / 256, 256, 0, stream>>>(counts, dinv);
    k_scatter  <<<(NEDGE + 255) / 256, 256, 0, stream>>>(ei, cursor, sortedSrc);
    k_smallmat <<<1, 256, 0, stream>>>(W1, b1, W2, M, cvec);
    k_agg1     <<<NTOKEN / 4, 256, 0, stream>>>(emb, dinv, rowStart, sortedSrc, Z1);
    k_out      <<<NPOS, 64, 0, stream>>>(inp, Z1, dinv, rowStart, sortedSrc, M, cvec, b2, out);
}

// Round 2
// 471.238 us; speedup vs baseline: 1.2828x; 1.2828x over previous
//
#include <hip/hip_runtime.h>
#include <hip/hip_bf16.h>

#define NTOKEN 150000
#define NINP   64
#define NHID   128
#define NEDGE  2400000
#define NPOS   (64*200)

// word (4-byte) offsets into workspace
#define O_DINV      0              // f32 [150000]
#define O_COUNTS    150016         // i32 [150000]
#define O_ROWSTART  300032         // i32 [150001]
#define O_CURSOR    450048         // i32 [150000]
#define O_BSUMS     600064         // i32 [256]
#define O_M         600320         // f32 [4096]   (W1@W2)
#define O_CVEC      604416         // f32 [64]     (b1@W2)
#define O_SORTED    604480         // i32 [2400000]
#define O_Z1        3004480        // f32 [150000*64]  (stores Z1s = dinv[v]*Z1[v], as float4)
// total ~50.5 MB

__global__ void k_count(const int4* __restrict__ dst4, int* __restrict__ counts) {
    int e = blockIdx.x * blockDim.x + threadIdx.x;
    if (e < NEDGE / 4) {
        int4 d = dst4[e];
        atomicAdd(&counts[d.x], 1);
        atomicAdd(&counts[d.y], 1);
        atomicAdd(&counts[d.z], 1);
        atomicAdd(&counts[d.w], 1);
    }
}

__global__ void k_scan_part(const int* __restrict__ counts, int* __restrict__ rowStart,
                            int* __restrict__ bsums) {
    __shared__ int sd[256];
    int tid = threadIdx.x;
    int base = blockIdx.x * 1024 + tid * 4;
    int c0 = (base + 0 < NTOKEN) ? counts[base + 0] : 0;
    int c1 = (base + 1 < NTOKEN) ? counts[base + 1] : 0;
    int c2 = (base + 2 < NTOKEN) ? counts[base + 2] : 0;
    int c3 = (base + 3 < NTOKEN) ? counts[base + 3] : 0;
    int tsum = c0 + c1 + c2 + c3;
    sd[tid] = tsum;
    __syncthreads();
    for (int off = 1; off < 256; off <<= 1) {
        int v = (tid >= off) ? sd[tid - off] : 0;
        __syncthreads();
        sd[tid] += v;
        __syncthreads();
    }
    int excl = sd[tid] - tsum;
    if (tid == 255) bsums[blockIdx.x] = sd[255];
    if (base + 0 < NTOKEN) rowStart[base + 0] = excl;
    if (base + 1 < NTOKEN) rowStart[base + 1] = excl + c0;
    if (base + 2 < NTOKEN) rowStart[base + 2] = excl + c0 + c1;
    if (base + 3 < NTOKEN) rowStart[base + 3] = excl + c0 + c1 + c2;
}

__global__ void k_scan_bsums(int* __restrict__ bsums, int nb) {
    __shared__ int sd[256];
    int tid = threadIdx.x;
    int v = (tid < nb) ? bsums[tid] : 0;
    sd[tid] = v;
    __syncthreads();
    for (int off = 1; off < 256; off <<= 1) {
        int t = (tid >= off) ? sd[tid - off] : 0;
        __syncthreads();
        sd[tid] += t;
        __syncthreads();
    }
    if (tid < nb) bsums[tid] = sd[tid] - v;  // exclusive
}

__global__ void k_scan_add(int* __restrict__ rowStart, int* __restrict__ cursor,
                           const int* __restrict__ bsums) {
    int tid = threadIdx.x;
    int base = blockIdx.x * 1024 + tid * 4;
    int add = bsums[blockIdx.x];
    for (int r = 0; r < 4; r++) {
        int i = base + r;
        if (i < NTOKEN) { int s = rowStart[i] + add; rowStart[i] = s; cursor[i] = s; }
    }
    if (blockIdx.x == 0 && tid == 0) rowStart[NTOKEN] = NEDGE;
}

__global__ void k_dinv(const int* __restrict__ counts, float* __restrict__ dinv) {
    int v = blockIdx.x * blockDim.x + threadIdx.x;
    if (v < NTOKEN) dinv[v] = rsqrtf((float)counts[v] + 1.0f);
}

__global__ void k_scatter(const int4* __restrict__ src4, const int4* __restrict__ dst4,
                          int* __restrict__ cursor, int* __restrict__ sortedSrc) {
    int e = blockIdx.x * blockDim.x + threadIdx.x;
    if (e < NEDGE / 4) {
        int4 s = src4[e];
        int4 d = dst4[e];
        sortedSrc[atomicAdd(&cursor[d.x], 1)] = s.x;
        sortedSrc[atomicAdd(&cursor[d.y], 1)] = s.y;
        sortedSrc[atomicAdd(&cursor[d.z], 1)] = s.z;
        sortedSrc[atomicAdd(&cursor[d.w], 1)] = s.w;
    }
}

// M = W1 @ W2  (64x64, K=128);  cvec = b1 @ W2  (64)
__global__ void k_smallmat(const float* __restrict__ W1, const float* __restrict__ b1,
                           const float* __restrict__ W2,
                           float* __restrict__ M, float* __restrict__ cvec) {
    int tid = threadIdx.x;
    for (int o = tid; o < 64 * 64; o += 256) {
        int i = o >> 6, j = o & 63;
        float s = 0.f;
        for (int k = 0; k < 128; k++) s += W1[i * 128 + k] * W2[k * 64 + j];
        M[o] = s;
    }
    if (tid < 64) {
        float s = 0.f;
        for (int k = 0; k < 128; k++) s += b1[k] * W2[k * 64 + tid];
        cvec[tid] = s;
    }
}

// Z1s[v] = dv^2 * ( sum_{u in N(v)} dinv[u]*X[u]  +  dv*X[v] )    (= dinv[v]*Z1[v])
// one wave per dst node; 4 groups of 16 lanes, float4 per lane -> 4 edges in flight
__global__ void k_agg1(const float4* __restrict__ X4, const float* __restrict__ dinv,
                       const int* __restrict__ rowStart, const int* __restrict__ sortedSrc,
                       float4* __restrict__ Z1s) {
    int wid = threadIdx.x >> 6;
    int lane = threadIdx.x & 63;
    int g = lane >> 4, fl = lane & 15;
    int v = blockIdx.x * 4 + wid;
    if (v >= NTOKEN) return;
    int e0 = rowStart[v], e1 = rowStart[v + 1];
    float ax = 0.f, ay = 0.f, az = 0.f, aw = 0.f;
    for (int e = e0 + g; e < e1; e += 4) {
        int u = sortedSrc[e];
        float du = dinv[u];
        float4 x = X4[(size_t)u * 16 + fl];
        ax = fmaf(du, x.x, ax); ay = fmaf(du, x.y, ay);
        az = fmaf(du, x.z, az); aw = fmaf(du, x.w, aw);
    }
    ax += __shfl_xor(ax, 16, 64); ay += __shfl_xor(ay, 16, 64);
    az += __shfl_xor(az, 16, 64); aw += __shfl_xor(aw, 16, 64);
    ax += __shfl_xor(ax, 32, 64); ay += __shfl_xor(ay, 32, 64);
    az += __shfl_xor(az, 32, 64); aw += __shfl_xor(aw, 32, 64);
    if (g == 0) {
        float dv = dinv[v];
        float c = dv * dv;
        float4 xs = X4[(size_t)v * 16 + fl];
        float4 o;
        o.x = c * fmaf(dv, xs.x, ax);
        o.y = c * fmaf(dv, xs.y, ay);
        o.z = c * fmaf(dv, xs.z, az);
        o.w = c * fmaf(dv, xs.w, aw);
        Z1s[(size_t)v * 16 + fl] = o;
    }
}

// out[p] = z2 @ M + s*cvec + b2
//   z2 = dv*( sum_u Z1s[u] + Z1s[v] ),  s = dv*( sum_u dinv[u] + dv )
__global__ void k_out(const int* __restrict__ inp, const float4* __restrict__ Z1s,
                      const float* __restrict__ dinv, const int* __restrict__ rowStart,
                      const int* __restrict__ sortedSrc, const float* __restrict__ M,
                      const float* __restrict__ cvec, const float* __restrict__ b2,
                      float* __restrict__ out) {
    int wid = threadIdx.x >> 6;
    int lane = threadIdx.x & 63;
    int g = lane >> 4, fl = lane & 15;
    int p = blockIdx.x * 4 + wid;
    if (p >= NPOS) return;
    int v = inp[p];
    int e0 = rowStart[v], e1 = rowStart[v + 1];
    float ax = 0.f, ay = 0.f, az = 0.f, aw = 0.f, ss = 0.f;
    for (int e = e0 + g; e < e1; e += 4) {
        int u = sortedSrc[e];
        ss += dinv[u];
        float4 z = Z1s[(size_t)u * 16 + fl];
        ax += z.x; ay += z.y; az += z.z; aw += z.w;
    }
    ax += __shfl_xor(ax, 16, 64); ay += __shfl_xor(ay, 16, 64);
    az += __shfl_xor(az, 16, 64); aw += __shfl_xor(aw, 16, 64);
    ss += __shfl_xor(ss, 16, 64);
    ax += __shfl_xor(ax, 32, 64); ay += __shfl_xor(ay, 32, 64);
    az += __shfl_xor(az, 32, 64); aw += __shfl_xor(aw, 32, 64);
    ss += __shfl_xor(ss, 32, 64);
    float dv = dinv[v];
    float4 zs = Z1s[(size_t)v * 16 + fl];
    float z2x = dv * (ax + zs.x);
    float z2y = dv * (ay + zs.y);
    float z2z = dv * (az + zs.z);
    float z2w = dv * (aw + zs.w);
    float s = dv * (ss + dv);
    float o = fmaf(s, cvec[lane], b2[lane]);
    #pragma unroll
    for (int kb = 0; kb < 16; kb++) {
        float a0 = __shfl(z2x, kb, 64);
        float a1 = __shfl(z2y, kb, 64);
        float a2 = __shfl(z2z, kb, 64);
        float a3 = __shfl(z2w, kb, 64);
        o = fmaf(a0, M[(kb * 4 + 0) * 64 + lane], o);
        o = fmaf(a1, M[(kb * 4 + 1) * 64 + lane], o);
        o = fmaf(a2, M[(kb * 4 + 2) * 64 + lane], o);
        o = fmaf(a3, M[(kb * 4 + 3) * 64 + lane], o);
    }
    out[(size_t)p * 64 + lane] = o;
}

extern "C" void kernel_launch(void* const* d_in, const int* in_sizes, int n_in,
                              void* d_out, int out_size, void* d_ws, size_t ws_size,
                              hipStream_t stream) {
    const float* emb = (const float*)d_in[0];
    const float* W1  = (const float*)d_in[1];
    const float* b1  = (const float*)d_in[2];
    const float* W2  = (const float*)d_in[3];
    const float* b2  = (const float*)d_in[4];
    const int*   inp = (const int*)d_in[5];
    // d_in[6] = input_timestamp (unused by the reference)
    const int*   ei  = (const int*)d_in[7];
    float* out = (float*)d_out;

    float* ws       = (float*)d_ws;
    float* dinv     = ws + O_DINV;
    int*   counts   = (int*)ws + O_COUNTS;
    int*   rowStart = (int*)ws + O_ROWSTART;
    int*   cursor   = (int*)ws + O_CURSOR;
    int*   bsums    = (int*)ws + O_BSUMS;
    float* M        = ws + O_M;
    float* cvec     = ws + O_CVEC;
    int*   sortedSrc= (int*)ws + O_SORTED;
    float* Z1       = ws + O_Z1;

    hipMemsetAsync(counts, 0, NTOKEN * sizeof(int), stream);

    k_count    <<<(NEDGE / 4 + 255) / 256, 256, 0, stream>>>((const int4*)(ei + NEDGE), counts);
    k_scan_part<<<147, 256, 0, stream>>>(counts, rowStart, bsums);
    k_scan_bsums<<<1, 256, 0, stream>>>(bsums, 147);
    k_scan_add <<<147, 256, 0, stream>>>(rowStart, cursor, bsums);
    k_dinv     <<<(NTOKEN + 255) / 256, 256, 0, stream>>>(counts, dinv);
    k_scatter  <<<(NEDGE / 4 + 255) / 256, 256, 0, stream>>>((const int4*)ei, (const int4*)(ei + NEDGE), cursor, sortedSrc);
    k_smallmat <<<1, 256, 0, stream>>>(W1, b1, W2, M, cvec);
    k_agg1     <<<NTOKEN / 4, 256, 0, stream>>>((const float4*)emb, dinv, rowStart, sortedSrc, (float4*)Z1);
    k_out      <<<NPOS / 4, 256, 0, stream>>>(inp, (const float4*)Z1, dinv, rowStart, sortedSrc, M, cvec, b2, out);
}

// Round 3
// 290.226 us; speedup vs baseline: 2.0829x; 1.6237x over previous
//
#include <hip/hip_runtime.h>
#include <hip/hip_bf16.h>

#define NTOKEN 150000
#define NINP   64
#define NEDGE  2400000
#define NPOS   (64*200)

#define NPB    256            // nodes per bucket (bucket = dst >> 8)
#define NBUCK  586            // ceil(NTOKEN / NPB)
#define EPB    8192           // edges per block in kA/kC
#define NBLK   293            // ceil(NEDGE / EPB)
#define CAP    6144           // LDS edge capacity per bucket (avg 4096, sigma~64)

// word (4-byte) offsets into workspace (total ~47 MiB)
#define O_Z1       0              // f32 [150000*64] Z1s = dinv[v]*Z1[v]; written in kE only
#define O_HIST     0              // i32 [NBLK*NBUCK=171698]; dead before Z1 written (kE)
#define O_CTOT     9600000        // i32 [586]
#define O_BSTART   9600640        // i32 [587]
#define O_DINV     9601280        // f32 [150000]
#define O_ROWSTART 9751296        // i32 [150001]
#define O_BUCK     9901312        // i32 [2400000] packed (src<<8|local); becomes sortedSrc in kE
#define O_M        12301312       // f32 [4096]  (W1@W2)
#define O_CVEC     12305408       // f32 [64]    (b1@W2)

// ---- Pass A: per-block bucket histogram (LDS atomics only) ----
__global__ void kA_hist(const int* __restrict__ dst, int* __restrict__ histG) {
    __shared__ int h[NBUCK];
    int tid = threadIdx.x;
    for (int i = tid; i < NBUCK; i += 256) h[i] = 0;
    __syncthreads();
    int base = blockIdx.x * EPB;
    #pragma unroll 4
    for (int i = 0; i < EPB / 256; i++) {
        int e = base + i * 256 + tid;
        if (e < NEDGE) atomicAdd(&h[dst[e] >> 8], 1);
    }
    __syncthreads();
    for (int i = tid; i < NBUCK; i += 256) histG[blockIdx.x * NBUCK + i] = h[i];
}

// ---- Pass B1: per-bucket column exclusive scan over blocks; one block per bucket ----
__global__ void kB1_colscan(int* __restrict__ histG, int* __restrict__ colTotal) {
    __shared__ int sd[256];
    int t = threadIdx.x, b = blockIdx.x;
    int i0 = 2 * t, i1 = 2 * t + 1;
    int v0 = (i0 < NBLK) ? histG[i0 * NBUCK + b] : 0;
    int v1 = (i1 < NBLK) ? histG[i1 * NBUCK + b] : 0;
    int tsum = v0 + v1;
    sd[t] = tsum;
    __syncthreads();
    for (int off = 1; off < 256; off <<= 1) {
        int x = (t >= off) ? sd[t - off] : 0;
        __syncthreads();
        sd[t] += x;
        __syncthreads();
    }
    int excl = sd[t] - tsum;
    if (i0 < NBLK) histG[i0 * NBUCK + b] = excl;
    if (i1 < NBLK) histG[i1 * NBUCK + b] = excl + v0;
    if (t == 255) colTotal[b] = sd[255];
}

// ---- Pass B2: exclusive scan of 586 bucket totals -> bucketStart ----
__global__ void kB2_scan(const int* __restrict__ colTotal, int* __restrict__ bucketStart) {
    __shared__ int sd[256];
    int t = threadIdx.x;
    int i0 = t * 3, i1 = t * 3 + 1, i2 = t * 3 + 2;
    int v0 = (i0 < NBUCK) ? colTotal[i0] : 0;
    int v1 = (i1 < NBUCK) ? colTotal[i1] : 0;
    int v2 = (i2 < NBUCK) ? colTotal[i2] : 0;
    int tsum = v0 + v1 + v2;
    sd[t] = tsum;
    __syncthreads();
    for (int off = 1; off < 256; off <<= 1) {
        int x = (t >= off) ? sd[t - off] : 0;
        __syncthreads();
        sd[t] += x;
        __syncthreads();
    }
    int excl = sd[t] - tsum;
    if (i0 < NBUCK) bucketStart[i0] = excl;
    if (i1 < NBUCK) bucketStart[i1] = excl + v0;
    if (i2 < NBUCK) bucketStart[i2] = excl + v0 + v1;
    if (t == 255) bucketStart[NBUCK] = NEDGE;
}

// ---- Pass C: scatter edges into bucket regions (LDS cursors, no global atomics) ----
__global__ void kC_scatter(const int* __restrict__ src, const int* __restrict__ dst,
                           const int* __restrict__ histG, const int* __restrict__ bucketStart,
                           int* __restrict__ bucketPacked) {
    __shared__ int cur[NBUCK];
    int tid = threadIdx.x;
    for (int i = tid; i < NBUCK; i += 256)
        cur[i] = histG[blockIdx.x * NBUCK + i] + bucketStart[i];
    __syncthreads();
    int base = blockIdx.x * EPB;
    #pragma unroll 4
    for (int i = 0; i < EPB / 256; i++) {
        int e = base + i * 256 + tid;
        if (e < NEDGE) {
            int d = dst[e];
            int b = d >> 8;
            int pos = atomicAdd(&cur[b], 1);
            bucketPacked[pos] = (src[e] << 8) | (d & 255);
        }
    }
}

// ---- Pass D: per-bucket degree count + scan -> dinv, rowStart ----
__global__ void kD_deg(const int* __restrict__ bucketPacked, const int* __restrict__ bucketStart,
                       float* __restrict__ dinv, int* __restrict__ rowStart) {
    __shared__ int cnt[NPB];
    __shared__ int sd[NPB];
    int t = threadIdx.x, b = blockIdx.x;
    cnt[t] = 0;
    __syncthreads();
    int e0 = bucketStart[b], e1 = bucketStart[b + 1];
    for (int e = e0 + t; e < e1; e += 256) atomicAdd(&cnt[bucketPacked[e] & 255], 1);
    __syncthreads();
    int c = cnt[t];
    sd[t] = c;
    __syncthreads();
    for (int off = 1; off < 256; off <<= 1) {
        int x = (t >= off) ? sd[t - off] : 0;
        __syncthreads();
        sd[t] += x;
        __syncthreads();
    }
    int excl = sd[t] - c;
    int node = b * NPB + t;
    if (node < NTOKEN) {
        dinv[node] = rsqrtf((float)c + 1.0f);
        rowStart[node] = e0 + excl;
    }
    if (b == NBUCK - 1 && t == 0) rowStart[NTOKEN] = NEDGE;
}

// ---- M = W1 @ W2 (64x64, K=128); cvec = b1 @ W2 ----
__global__ void k_smallmat(const float* __restrict__ W1, const float* __restrict__ b1,
                           const float* __restrict__ W2,
                           float* __restrict__ M, float* __restrict__ cvec) {
    int tid = threadIdx.x;
    for (int o = tid; o < 64 * 64; o += 256) {
        int i = o >> 6, j = o & 63;
        float s = 0.f;
        for (int k = 0; k < 128; k++) s += W1[i * 128 + k] * W2[k * 64 + j];
        M[o] = s;
    }
    if (tid < 64) {
        float s = 0.f;
        for (int k = 0; k < 128; k++) s += b1[k] * W2[k * 64 + tid];
        cvec[tid] = s;
    }
}

// ---- Pass E: per-bucket local CSR build in LDS + coalesced CSR dump + aggregation ----
// Z1s[v] = dv^2 * ( sum_{u in N(v)} dinv[u]*X[u] + dv*X[v] )
__global__ void kE_agg(const float4* __restrict__ X4, const float* __restrict__ dinv,
                       const int* __restrict__ bucketStart, const int* __restrict__ rowStart,
                       int* __restrict__ bucketPacked /* in: packed; out: sortedSrc */,
                       float4* __restrict__ Z1s) {
    __shared__ int srcSorted[CAP];
    __shared__ int cur[NPB];
    int t = threadIdx.x, b = blockIdx.x;
    int e0 = bucketStart[b], e1 = bucketStart[b + 1];
    int nE = e1 - e0;
    int node = b * NPB + t;
    cur[t] = (node < NTOKEN) ? (rowStart[node] - e0) : nE;
    __syncthreads();
    for (int e = e0 + t; e < e1; e += 256) {
        int p = bucketPacked[e];
        int pos = atomicAdd(&cur[p & 255], 1);
        if (pos < CAP) srcSorted[pos] = p >> 8;
    }
    __syncthreads();
    // dump global CSR into the same region (all reads of bucketPacked done above)
    for (int i = t; i < nE; i += 256) bucketPacked[e0 + i] = srcSorted[i];
    // aggregate: 4 waves; 4 groups of 16 lanes, float4 per lane
    int wid = t >> 6, lane = t & 63, g = lane >> 4, fl = lane & 15;
    for (int l = wid; l < NPB; l += 4) {
        int v = b * NPB + l;
        if (v >= NTOKEN) break;
        int ls = rowStart[v] - e0, le = rowStart[v + 1] - e0;
        float ax = 0.f, ay = 0.f, az = 0.f, aw = 0.f;
        for (int e = ls + g; e < le; e += 4) {
            int u = srcSorted[e];
            float du = dinv[u];
            float4 x = X4[(size_t)u * 16 + fl];
            ax = fmaf(du, x.x, ax); ay = fmaf(du, x.y, ay);
            az = fmaf(du, x.z, az); aw = fmaf(du, x.w, aw);
        }
        ax += __shfl_xor(ax, 16, 64); ay += __shfl_xor(ay, 16, 64);
        az += __shfl_xor(az, 16, 64); aw += __shfl_xor(aw, 16, 64);
        ax += __shfl_xor(ax, 32, 64); ay += __shfl_xor(ay, 32, 64);
        az += __shfl_xor(az, 32, 64); aw += __shfl_xor(aw, 32, 64);
        if (g == 0) {
            float dv = dinv[v];
            float cdv = dv * dv;
            float4 xs = X4[(size_t)v * 16 + fl];
            float4 o;
            o.x = cdv * fmaf(dv, xs.x, ax);
            o.y = cdv * fmaf(dv, xs.y, ay);
            o.z = cdv * fmaf(dv, xs.z, az);
            o.w = cdv * fmaf(dv, xs.w, aw);
            Z1s[(size_t)v * 16 + fl] = o;
        }
    }
}

// ---- out[p] = z2 @ M + s*cvec + b2 ----
__global__ void k_out(const int* __restrict__ inp, const float4* __restrict__ Z1s,
                      const float* __restrict__ dinv, const int* __restrict__ rowStart,
                      const int* __restrict__ sortedSrc, const float* __restrict__ M,
                      const float* __restrict__ cvec, const float* __restrict__ b2,
                      float* __restrict__ out) {
    int wid = threadIdx.x >> 6;
    int lane = threadIdx.x & 63;
    int g = lane >> 4, fl = lane & 15;
    int p = blockIdx.x * 4 + wid;
    if (p >= NPOS) return;
    int v = inp[p];
    int e0 = rowStart[v], e1 = rowStart[v + 1];
    float ax = 0.f, ay = 0.f, az = 0.f, aw = 0.f, ss = 0.f;
    for (int e = e0 + g; e < e1; e += 4) {
        int u = sortedSrc[e];
        ss += dinv[u];
        float4 z = Z1s[(size_t)u * 16 + fl];
        ax += z.x; ay += z.y; az += z.z; aw += z.w;
    }
    ax += __shfl_xor(ax, 16, 64); ay += __shfl_xor(ay, 16, 64);
    az += __shfl_xor(az, 16, 64); aw += __shfl_xor(aw, 16, 64);
    ss += __shfl_xor(ss, 16, 64);
    ax += __shfl_xor(ax, 32, 64); ay += __shfl_xor(ay, 32, 64);
    az += __shfl_xor(az, 32, 64); aw += __shfl_xor(aw, 32, 64);
    ss += __shfl_xor(ss, 32, 64);
    float dv = dinv[v];
    float4 zs = Z1s[(size_t)v * 16 + fl];
    float z2x = dv * (ax + zs.x);
    float z2y = dv * (ay + zs.y);
    float z2z = dv * (az + zs.z);
    float z2w = dv * (aw + zs.w);
    float s = dv * (ss + dv);
    float o = fmaf(s, cvec[lane], b2[lane]);
    #pragma unroll
    for (int kb = 0; kb < 16; kb++) {
        float a0 = __shfl(z2x, kb, 64);
        float a1 = __shfl(z2y, kb, 64);
        float a2 = __shfl(z2z, kb, 64);
        float a3 = __shfl(z2w, kb, 64);
        o = fmaf(a0, M[(kb * 4 + 0) * 64 + lane], o);
        o = fmaf(a1, M[(kb * 4 + 1) * 64 + lane], o);
        o = fmaf(a2, M[(kb * 4 + 2) * 64 + lane], o);
        o = fmaf(a3, M[(kb * 4 + 3) * 64 + lane], o);
    }
    out[(size_t)p * 64 + lane] = o;
}

extern "C" void kernel_launch(void* const* d_in, const int* in_sizes, int n_in,
                              void* d_out, int out_size, void* d_ws, size_t ws_size,
                              hipStream_t stream) {
    const float* emb = (const float*)d_in[0];
    const float* W1  = (const float*)d_in[1];
    const float* b1  = (const float*)d_in[2];
    const float* W2  = (const float*)d_in[3];
    const float* b2  = (const float*)d_in[4];
    const int*   inp = (const int*)d_in[5];
    // d_in[6] = input_timestamp (unused by the reference)
    const int*   ei  = (const int*)d_in[7];
    const int* srcArr = ei;
    const int* dstArr = ei + NEDGE;
    float* out = (float*)d_out;

    float* ws         = (float*)d_ws;
    float* Z1s        = ws + O_Z1;
    int*   histG      = (int*)ws + O_HIST;
    int*   colTotal   = (int*)ws + O_CTOT;
    int*   bucketStart= (int*)ws + O_BSTART;
    float* dinv       = ws + O_DINV;
    int*   rowStart   = (int*)ws + O_ROWSTART;
    int*   buckPacked = (int*)ws + O_BUCK;     // becomes sortedSrc after kE
    float* M          = ws + O_M;
    float* cvec       = ws + O_CVEC;

    kA_hist    <<<NBLK,  256, 0, stream>>>(dstArr, histG);
    kB1_colscan<<<NBUCK, 256, 0, stream>>>(histG, colTotal);
    kB2_scan   <<<1,     256, 0, stream>>>(colTotal, bucketStart);
    kC_scatter <<<NBLK,  256, 0, stream>>>(srcArr, dstArr, histG, bucketStart, buckPacked);
    kD_deg     <<<NBUCK, 256, 0, stream>>>(buckPacked, bucketStart, dinv, rowStart);
    k_smallmat <<<1,     256, 0, stream>>>(W1, b1, W2, M, cvec);
    kE_agg     <<<NBUCK, 256, 0, stream>>>((const float4*)emb, dinv, bucketStart, rowStart,
                                           buckPacked, (float4*)Z1s);
    k_out      <<<NPOS/4, 256, 0, stream>>>(inp, (const float4*)Z1s, dinv, rowStart,
                                            buckPacked, M, cvec, b2, out);
}

// Round 4
// 233.165 us; speedup vs baseline: 2.5927x; 1.2447x over previous
//
#include <hip/hip_runtime.h>
#include <hip/hip_bf16.h>

#define NTOKEN 150000
#define NINP   64
#define NEDGE  2400000
#define NPOS   (64*200)

#define NPB    256            // nodes per bucket (bucket = dst >> 8)
#define NBUCK  586            // ceil(NTOKEN / NPB)
#define EPB    8192           // edges per block in kA/kC
#define NBLK   293            // ceil(NEDGE / EPB)
#define CAP    6144           // LDS edge capacity per bucket (avg 4096, sigma~64)

// word (4-byte) offsets into workspace (total ~50.4 MiB)
#define O_Z1       0              // f32 [150000*64]; written in k_agg (after histG dead)
#define O_HIST     0              // i32 [NBLK*NBUCK=171698]; last read in kC
#define O_CTOT     9600000        // i32 [586]
#define O_BSTART   9600640        // i32 [587]
#define O_DINV     9601280        // f32 [150000]
#define O_ROWSTART 9751296        // i32 [150001]
#define O_BUCK     9901312        // i32 [2400000] packed (src<<8|local); sorted in place by kE
#define O_M        12301312       // f32 [4096]  (W1@W2)
#define O_CVEC     12305408       // f32 [64]    (b1@W2)

// ---- Pass A: per-block bucket histogram (LDS atomics only) ----
__global__ void kA_hist(const int* __restrict__ dst, int* __restrict__ histG) {
    __shared__ int h[NBUCK];
    int tid = threadIdx.x;
    for (int i = tid; i < NBUCK; i += 256) h[i] = 0;
    __syncthreads();
    int base = blockIdx.x * EPB;
    #pragma unroll 4
    for (int i = 0; i < EPB / 256; i++) {
        int e = base + i * 256 + tid;
        if (e < NEDGE) atomicAdd(&h[dst[e] >> 8], 1);
    }
    __syncthreads();
    for (int i = tid; i < NBUCK; i += 256) histG[blockIdx.x * NBUCK + i] = h[i];
}

// ---- Pass B1: per-bucket column exclusive scan over blocks; one block per bucket ----
__global__ void kB1_colscan(int* __restrict__ histG, int* __restrict__ colTotal) {
    __shared__ int sd[256];
    int t = threadIdx.x, b = blockIdx.x;
    int i0 = 2 * t, i1 = 2 * t + 1;
    int v0 = (i0 < NBLK) ? histG[i0 * NBUCK + b] : 0;
    int v1 = (i1 < NBLK) ? histG[i1 * NBUCK + b] : 0;
    int tsum = v0 + v1;
    sd[t] = tsum;
    __syncthreads();
    for (int off = 1; off < 256; off <<= 1) {
        int x = (t >= off) ? sd[t - off] : 0;
        __syncthreads();
        sd[t] += x;
        __syncthreads();
    }
    int excl = sd[t] - tsum;
    if (i0 < NBLK) histG[i0 * NBUCK + b] = excl;
    if (i1 < NBLK) histG[i1 * NBUCK + b] = excl + v0;
    if (t == 255) colTotal[b] = sd[255];
}

// ---- Pass B2: exclusive scan of 586 bucket totals -> bucketStart ----
__global__ void kB2_scan(const int* __restrict__ colTotal, int* __restrict__ bucketStart) {
    __shared__ int sd[256];
    int t = threadIdx.x;
    int i0 = t * 3, i1 = t * 3 + 1, i2 = t * 3 + 2;
    int v0 = (i0 < NBUCK) ? colTotal[i0] : 0;
    int v1 = (i1 < NBUCK) ? colTotal[i1] : 0;
    int v2 = (i2 < NBUCK) ? colTotal[i2] : 0;
    int tsum = v0 + v1 + v2;
    sd[t] = tsum;
    __syncthreads();
    for (int off = 1; off < 256; off <<= 1) {
        int x = (t >= off) ? sd[t - off] : 0;
        __syncthreads();
        sd[t] += x;
        __syncthreads();
    }
    int excl = sd[t] - tsum;
    if (i0 < NBUCK) bucketStart[i0] = excl;
    if (i1 < NBUCK) bucketStart[i1] = excl + v0;
    if (i2 < NBUCK) bucketStart[i2] = excl + v0 + v1;
    if (t == 255) bucketStart[NBUCK] = NEDGE;
}

// ---- Pass C: scatter edges into bucket regions (LDS cursors, no global atomics) ----
__global__ void kC_scatter(const int* __restrict__ src, const int* __restrict__ dst,
                           const int* __restrict__ histG, const int* __restrict__ bucketStart,
                           int* __restrict__ bucketPacked) {
    __shared__ int cur[NBUCK];
    int tid = threadIdx.x;
    for (int i = tid; i < NBUCK; i += 256)
        cur[i] = histG[blockIdx.x * NBUCK + i] + bucketStart[i];
    __syncthreads();
    int base = blockIdx.x * EPB;
    #pragma unroll 4
    for (int i = 0; i < EPB / 256; i++) {
        int e = base + i * 256 + tid;
        if (e < NEDGE) {
            int d = dst[e];
            int b = d >> 8;
            int pos = atomicAdd(&cur[b], 1);
            bucketPacked[pos] = (src[e] << 8) | (d & 255);
        }
    }
}

// ---- Pass D: per-bucket degree count + scan -> dinv, rowStart ----
__global__ void kD_deg(const int* __restrict__ bucketPacked, const int* __restrict__ bucketStart,
                       float* __restrict__ dinv, int* __restrict__ rowStart) {
    __shared__ int cnt[NPB];
    __shared__ int sd[NPB];
    int t = threadIdx.x, b = blockIdx.x;
    cnt[t] = 0;
    __syncthreads();
    int e0 = bucketStart[b], e1 = bucketStart[b + 1];
    for (int e = e0 + t; e < e1; e += 256) atomicAdd(&cnt[bucketPacked[e] & 255], 1);
    __syncthreads();
    int c = cnt[t];
    sd[t] = c;
    __syncthreads();
    for (int off = 1; off < 256; off <<= 1) {
        int x = (t >= off) ? sd[t - off] : 0;
        __syncthreads();
        sd[t] += x;
        __syncthreads();
    }
    int excl = sd[t] - c;
    int node = b * NPB + t;
    if (node < NTOKEN) {
        dinv[node] = rsqrtf((float)c + 1.0f);
        rowStart[node] = e0 + excl;
    }
    if (b == NBUCK - 1 && t == 0) rowStart[NTOKEN] = NEDGE;
}

// ---- M = W1 @ W2 (64x64, K=128); cvec = b1 @ W2 ----
__global__ void k_smallmat(const float* __restrict__ W1, const float* __restrict__ b1,
                           const float* __restrict__ W2,
                           float* __restrict__ M, float* __restrict__ cvec) {
    int tid = threadIdx.x;
    for (int o = tid; o < 64 * 64; o += 256) {
        int i = o >> 6, j = o & 63;
        float s = 0.f;
        for (int k = 0; k < 128; k++) s += W1[i * 128 + k] * W2[k * 64 + j];
        M[o] = s;
    }
    if (tid < 64) {
        float s = 0.f;
        for (int k = 0; k < 128; k++) s += b1[k] * W2[k * 64 + tid];
        cvec[tid] = s;
    }
}

// ---- Pass E: per-bucket LDS counting sort; in-place coalesced CSR dump ----
__global__ void kE_sort(const int* __restrict__ bucketStart, const int* __restrict__ rowStart,
                        int* __restrict__ bucketPacked /* in: packed; out: sortedSrc */) {
    __shared__ int srcSorted[CAP];
    __shared__ int cur[NPB];
    int t = threadIdx.x, b = blockIdx.x;
    int e0 = bucketStart[b], e1 = bucketStart[b + 1];
    int nE = e1 - e0;
    int node = b * NPB + t;
    cur[t] = (node < NTOKEN) ? (rowStart[node] - e0) : nE;
    __syncthreads();
    for (int e = e0 + t; e < e1; e += 256) {
        int p = bucketPacked[e];
        int pos = atomicAdd(&cur[p & 255], 1);
        if (pos < CAP) srcSorted[pos] = p >> 8;
    }
    __syncthreads();
    for (int i = t; i < nE; i += 256) bucketPacked[e0 + i] = srcSorted[i];
}

// ---- Z1s[v] = dv^2*( sum_u dinv[u]*X[u] + dv*X[v] ); one wave/node, 4x16 groups, unroll 2 ----
__global__ void k_agg(const float4* __restrict__ X4, const float* __restrict__ dinv,
                      const int* __restrict__ rowStart, const int* __restrict__ sortedSrc,
                      float4* __restrict__ Z1s) {
    int wid = threadIdx.x >> 6, lane = threadIdx.x & 63;
    int g = lane >> 4, fl = lane & 15;
    int v = blockIdx.x * 4 + wid;
    int e0 = rowStart[v], e1 = rowStart[v + 1];
    float ax0 = 0.f, ay0 = 0.f, az0 = 0.f, aw0 = 0.f;
    float ax1 = 0.f, ay1 = 0.f, az1 = 0.f, aw1 = 0.f;
    int e = e0 + g;
    for (; e + 4 < e1; e += 8) {
        int u0 = sortedSrc[e];
        int u1 = sortedSrc[e + 4];
        float d0 = dinv[u0], d1 = dinv[u1];
        float4 x0 = X4[(size_t)u0 * 16 + fl];
        float4 x1 = X4[(size_t)u1 * 16 + fl];
        ax0 = fmaf(d0, x0.x, ax0); ay0 = fmaf(d0, x0.y, ay0);
        az0 = fmaf(d0, x0.z, az0); aw0 = fmaf(d0, x0.w, aw0);
        ax1 = fmaf(d1, x1.x, ax1); ay1 = fmaf(d1, x1.y, ay1);
        az1 = fmaf(d1, x1.z, az1); aw1 = fmaf(d1, x1.w, aw1);
    }
    if (e < e1) {
        int u = sortedSrc[e];
        float d = dinv[u];
        float4 x = X4[(size_t)u * 16 + fl];
        ax0 = fmaf(d, x.x, ax0); ay0 = fmaf(d, x.y, ay0);
        az0 = fmaf(d, x.z, az0); aw0 = fmaf(d, x.w, aw0);
    }
    float ax = ax0 + ax1, ay = ay0 + ay1, az = az0 + az1, aw = aw0 + aw1;
    ax += __shfl_xor(ax, 16, 64); ay += __shfl_xor(ay, 16, 64);
    az += __shfl_xor(az, 16, 64); aw += __shfl_xor(aw, 16, 64);
    ax += __shfl_xor(ax, 32, 64); ay += __shfl_xor(ay, 32, 64);
    az += __shfl_xor(az, 32, 64); aw += __shfl_xor(aw, 32, 64);
    if (g == 0) {
        float dv = dinv[v];
        float c = dv * dv;
        float4 xs = X4[(size_t)v * 16 + fl];
        float4 o;
        o.x = c * fmaf(dv, xs.x, ax);
        o.y = c * fmaf(dv, xs.y, ay);
        o.z = c * fmaf(dv, xs.z, az);
        o.w = c * fmaf(dv, xs.w, aw);
        Z1s[(size_t)v * 16 + fl] = o;
    }
}

// ---- out[p] = z2 @ M + s*cvec + b2 ----
__global__ void k_out(const int* __restrict__ inp, const float4* __restrict__ Z1s,
                      const float* __restrict__ dinv, const int* __restrict__ rowStart,
                      const int* __restrict__ sortedSrc, const float* __restrict__ M,
                      const float* __restrict__ cvec, const float* __restrict__ b2,
                      float* __restrict__ out) {
    int wid = threadIdx.x >> 6;
    int lane = threadIdx.x & 63;
    int g = lane >> 4, fl = lane & 15;
    int p = blockIdx.x * 4 + wid;
    if (p >= NPOS) return;
    int v = inp[p];
    int e0 = rowStart[v], e1 = rowStart[v + 1];
    float ax0 = 0.f, ay0 = 0.f, az0 = 0.f, aw0 = 0.f, ss0 = 0.f;
    float ax1 = 0.f, ay1 = 0.f, az1 = 0.f, aw1 = 0.f, ss1 = 0.f;
    int e = e0 + g;
    for (; e + 4 < e1; e += 8) {
        int u0 = sortedSrc[e];
        int u1 = sortedSrc[e + 4];
        ss0 += dinv[u0]; ss1 += dinv[u1];
        float4 z0 = Z1s[(size_t)u0 * 16 + fl];
        float4 z1 = Z1s[(size_t)u1 * 16 + fl];
        ax0 += z0.x; ay0 += z0.y; az0 += z0.z; aw0 += z0.w;
        ax1 += z1.x; ay1 += z1.y; az1 += z1.z; aw1 += z1.w;
    }
    if (e < e1) {
        int u = sortedSrc[e];
        ss0 += dinv[u];
        float4 z = Z1s[(size_t)u * 16 + fl];
        ax0 += z.x; ay0 += z.y; az0 += z.z; aw0 += z.w;
    }
    float ax = ax0 + ax1, ay = ay0 + ay1, az = az0 + az1, aw = aw0 + aw1, ss = ss0 + ss1;
    ax += __shfl_xor(ax, 16, 64); ay += __shfl_xor(ay, 16, 64);
    az += __shfl_xor(az, 16, 64); aw += __shfl_xor(aw, 16, 64);
    ss += __shfl_xor(ss, 16, 64);
    ax += __shfl_xor(ax, 32, 64); ay += __shfl_xor(ay, 32, 64);
    az += __shfl_xor(az, 32, 64); aw += __shfl_xor(aw, 32, 64);
    ss += __shfl_xor(ss, 32, 64);
    float dv = dinv[v];
    float4 zs = Z1s[(size_t)v * 16 + fl];
    float z2x = dv * (ax + zs.x);
    float z2y = dv * (ay + zs.y);
    float z2z = dv * (az + zs.z);
    float z2w = dv * (aw + zs.w);
    float s = dv * (ss + dv);
    float o = fmaf(s, cvec[lane], b2[lane]);
    #pragma unroll
    for (int kb = 0; kb < 16; kb++) {
        float a0 = __shfl(z2x, kb, 64);
        float a1 = __shfl(z2y, kb, 64);
        float a2 = __shfl(z2z, kb, 64);
        float a3 = __shfl(z2w, kb, 64);
        o = fmaf(a0, M[(kb * 4 + 0) * 64 + lane], o);
        o = fmaf(a1, M[(kb * 4 + 1) * 64 + lane], o);
        o = fmaf(a2, M[(kb * 4 + 2) * 64 + lane], o);
        o = fmaf(a3, M[(kb * 4 + 3) * 64 + lane], o);
    }
    out[(size_t)p * 64 + lane] = o;
}

extern "C" void kernel_launch(void* const* d_in, const int* in_sizes, int n_in,
                              void* d_out, int out_size, void* d_ws, size_t ws_size,
                              hipStream_t stream) {
    const float* emb = (const float*)d_in[0];
    const float* W1  = (const float*)d_in[1];
    const float* b1  = (const float*)d_in[2];
    const float* W2  = (const float*)d_in[3];
    const float* b2  = (const float*)d_in[4];
    const int*   inp = (const int*)d_in[5];
    // d_in[6] = input_timestamp (unused by the reference)
    const int*   ei  = (const int*)d_in[7];
    const int* srcArr = ei;
    const int* dstArr = ei + NEDGE;
    float* out = (float*)d_out;

    float* ws         = (float*)d_ws;
    float* Z1s        = ws + O_Z1;
    int*   histG      = (int*)ws + O_HIST;
    int*   colTotal   = (int*)ws + O_CTOT;
    int*   bucketStart= (int*)ws + O_BSTART;
    float* dinv       = ws + O_DINV;
    int*   rowStart   = (int*)ws + O_ROWSTART;
    int*   buckPacked = (int*)ws + O_BUCK;     // becomes sortedSrc after kE_sort
    float* M          = ws + O_M;
    float* cvec       = ws + O_CVEC;

    kA_hist    <<<NBLK,  256, 0, stream>>>(dstArr, histG);
    kB1_colscan<<<NBUCK, 256, 0, stream>>>(histG, colTotal);
    kB2_scan   <<<1,     256, 0, stream>>>(colTotal, bucketStart);
    kC_scatter <<<NBLK,  256, 0, stream>>>(srcArr, dstArr, histG, bucketStart, buckPacked);
    kD_deg     <<<NBUCK, 256, 0, stream>>>(buckPacked, bucketStart, dinv, rowStart);
    k_smallmat <<<1,     256, 0, stream>>>(W1, b1, W2, M, cvec);
    kE_sort    <<<NBUCK, 256, 0, stream>>>(bucketStart, rowStart, buckPacked);
    k_agg      <<<NTOKEN/4, 256, 0, stream>>>((const float4*)emb, dinv, rowStart,
                                              buckPacked, (float4*)Z1s);
    k_out      <<<NPOS/4, 256, 0, stream>>>(inp, (const float4*)Z1s, dinv, rowStart,
                                            buckPacked, M, cvec, b2, out);
}

// Round 5
// 174.671 us; speedup vs baseline: 3.4609x; 1.3349x over previous
//
#include <hip/hip_runtime.h>
#include <hip/hip_bf16.h>

#define NTOKEN 150000
#define NINP   64
#define NEDGE  2400000
#define NPOS   (64*200)

#define NPB    256            // nodes per bucket (bucket = dst >> 8)
#define NBUCK  586            // ceil(NTOKEN / NPB)
#define EPB    8192           // edges per block in kA/kC
#define NBLK   293            // ceil(NEDGE / EPB)
#define CAP    6144           // LDS edge capacity per bucket (avg 4096, sigma~64)

// word (4-byte) offsets into workspace (total ~50.4 MiB)
#define O_Z1       0              // f32 [150000*64]; written in k_agg (after histG dead)
#define O_HIST     0              // i32 [NBLK*NBUCK=171698]; last read in kC
#define O_CTOT     9600000        // i32 [586]
#define O_BSTART   9600640        // i32 [587]
#define O_DINV     9601280        // f32 [150000]
#define O_ROWSTART 9751296        // i32 [150001]
#define O_BUCK     9901312        // i32 [2400000] packed (src<<8|local); sorted in place by kDE
#define O_M        12301312       // f32 [4096]  (W1@W2)
#define O_CVEC     12305408       // f32 [64]    (b1@W2)

// ---- Pass A: per-block bucket histogram (LDS atomics only) ----
__global__ void kA_hist(const int* __restrict__ dst, int* __restrict__ histG) {
    __shared__ int h[NBUCK];
    int tid = threadIdx.x;
    for (int i = tid; i < NBUCK; i += 1024) h[i] = 0;
    __syncthreads();
    int base = blockIdx.x * EPB;
    #pragma unroll
    for (int i = 0; i < EPB / 1024; i++) {
        int e = base + i * 1024 + tid;
        if (e < NEDGE) atomicAdd(&h[dst[e] >> 8], 1);
    }
    __syncthreads();
    for (int i = tid; i < NBUCK; i += 1024) histG[blockIdx.x * NBUCK + i] = h[i];
}

// ---- Pass B1: per-bucket column exclusive scan over blocks; one block per bucket ----
__global__ void kB1_colscan(int* __restrict__ histG, int* __restrict__ colTotal) {
    __shared__ int sd[256];
    int t = threadIdx.x, b = blockIdx.x;
    int i0 = 2 * t, i1 = 2 * t + 1;
    int v0 = (i0 < NBLK) ? histG[i0 * NBUCK + b] : 0;
    int v1 = (i1 < NBLK) ? histG[i1 * NBUCK + b] : 0;
    int tsum = v0 + v1;
    sd[t] = tsum;
    __syncthreads();
    for (int off = 1; off < 256; off <<= 1) {
        int x = (t >= off) ? sd[t - off] : 0;
        __syncthreads();
        sd[t] += x;
        __syncthreads();
    }
    int excl = sd[t] - tsum;
    if (i0 < NBLK) histG[i0 * NBUCK + b] = excl;
    if (i1 < NBLK) histG[i1 * NBUCK + b] = excl + v0;
    if (t == 255) colTotal[b] = sd[255];
}

// ---- Pass B2: exclusive scan of 586 bucket totals -> bucketStart ----
__global__ void kB2_scan(const int* __restrict__ colTotal, int* __restrict__ bucketStart) {
    __shared__ int sd[256];
    int t = threadIdx.x;
    int i0 = t * 3, i1 = t * 3 + 1, i2 = t * 3 + 2;
    int v0 = (i0 < NBUCK) ? colTotal[i0] : 0;
    int v1 = (i1 < NBUCK) ? colTotal[i1] : 0;
    int v2 = (i2 < NBUCK) ? colTotal[i2] : 0;
    int tsum = v0 + v1 + v2;
    sd[t] = tsum;
    __syncthreads();
    for (int off = 1; off < 256; off <<= 1) {
        int x = (t >= off) ? sd[t - off] : 0;
        __syncthreads();
        sd[t] += x;
        __syncthreads();
    }
    int excl = sd[t] - tsum;
    if (i0 < NBUCK) bucketStart[i0] = excl;
    if (i1 < NBUCK) bucketStart[i1] = excl + v0;
    if (i2 < NBUCK) bucketStart[i2] = excl + v0 + v1;
    if (t == 255) bucketStart[NBUCK] = NEDGE;
}

// ---- Pass C: scatter edges into bucket regions (LDS cursors, no global atomics) ----
__global__ void kC_scatter(const int* __restrict__ src, const int* __restrict__ dst,
                           const int* __restrict__ histG, const int* __restrict__ bucketStart,
                           int* __restrict__ bucketPacked) {
    __shared__ int cur[NBUCK];
    int tid = threadIdx.x;
    for (int i = tid; i < NBUCK; i += 1024)
        cur[i] = histG[blockIdx.x * NBUCK + i] + bucketStart[i];
    __syncthreads();
    int base = blockIdx.x * EPB;
    #pragma unroll
    for (int i = 0; i < EPB / 1024; i++) {
        int e = base + i * 1024 + tid;
        if (e < NEDGE) {
            int d = dst[e];
            int b = d >> 8;
            int pos = atomicAdd(&cur[b], 1);
            bucketPacked[pos] = (src[e] << 8) | (d & 255);
        }
    }
}

// ---- Pass DE (fused kD+kE): per-bucket count+scan -> dinv/rowStart; LDS sort; CSR dump ----
__global__ void kDE(const int* __restrict__ bucketStart,
                    int* __restrict__ bucketPacked /* in: packed; out: sortedSrc */,
                    float* __restrict__ dinv, int* __restrict__ rowStart) {
    __shared__ int raw[CAP];
    __shared__ int srt[CAP];
    __shared__ int cnt[NPB];
    __shared__ int sd[NPB];
    int t = threadIdx.x, b = blockIdx.x;
    int e0 = bucketStart[b], e1 = bucketStart[b + 1];
    int nE = e1 - e0;
    int nEc = (nE < CAP) ? nE : CAP;
    if (t < NPB) cnt[t] = 0;
    __syncthreads();
    for (int i = t; i < nEc; i += 1024) {
        int p = bucketPacked[e0 + i];
        raw[i] = p;
        atomicAdd(&cnt[p & 255], 1);
    }
    __syncthreads();
    int c = 0;
    if (t < NPB) { c = cnt[t]; sd[t] = c; }
    __syncthreads();
    for (int off = 1; off < 256; off <<= 1) {
        int x = 0;
        if (t < NPB && t >= off) x = sd[t - off];
        __syncthreads();
        if (t < NPB) sd[t] += x;
        __syncthreads();
    }
    if (t < NPB) {
        int excl = sd[t] - c;
        cnt[t] = excl;                    // becomes cursor
        int node = b * NPB + t;
        if (node < NTOKEN) {
            dinv[node] = rsqrtf((float)c + 1.0f);
            rowStart[node] = e0 + excl;
        }
        if (b == NBUCK - 1 && t == 0) rowStart[NTOKEN] = NEDGE;
    }
    __syncthreads();
    for (int i = t; i < nEc; i += 1024) {
        int p = raw[i];
        int pos = atomicAdd(&cnt[p & 255], 1);
        if (pos < CAP) srt[pos] = p >> 8;
    }
    __syncthreads();
    for (int i = t; i < nEc; i += 1024) bucketPacked[e0 + i] = srt[i];
}

// ---- M = W1 @ W2 (64x64, K=128); cvec = b1 @ W2; 17 blocks ----
__global__ void k_smallmat(const float* __restrict__ W1, const float* __restrict__ b1,
                           const float* __restrict__ W2,
                           float* __restrict__ M, float* __restrict__ cvec) {
    int bb = blockIdx.x;
    if (bb < 16) {
        int o = bb * 256 + threadIdx.x;
        int i = o >> 6, j = o & 63;
        float s = 0.f;
        #pragma unroll 4
        for (int k = 0; k < 128; k++) s = fmaf(W1[i * 128 + k], W2[k * 64 + j], s);
        M[o] = s;
    } else if (threadIdx.x < 64) {
        float s = 0.f;
        #pragma unroll 4
        for (int k = 0; k < 128; k++) s = fmaf(b1[k], W2[k * 64 + threadIdx.x], s);
        cvec[threadIdx.x] = s;
    }
}

// ---- Z1s[v] = dv^2*( sum_u dinv[u]*X[u] + dv*X[v] ); one 16-lane group per node, unroll 4 ----
__global__ void k_agg(const float4* __restrict__ X4, const float* __restrict__ dinv,
                      const int* __restrict__ rowStart, const int* __restrict__ sortedSrc,
                      float4* __restrict__ Z1s) {
    int g = threadIdx.x >> 4;           // 16 groups per block
    int fl = threadIdx.x & 15;
    int v = blockIdx.x * 16 + g;        // grid*16 == NTOKEN exactly
    int e0 = rowStart[v], e1 = rowStart[v + 1];
    float ax0 = 0.f, ay0 = 0.f, az0 = 0.f, aw0 = 0.f;
    float ax1 = 0.f, ay1 = 0.f, az1 = 0.f, aw1 = 0.f;
    float ax2 = 0.f, ay2 = 0.f, az2 = 0.f, aw2 = 0.f;
    float ax3 = 0.f, ay3 = 0.f, az3 = 0.f, aw3 = 0.f;
    int e = e0;
    for (; e + 3 < e1; e += 4) {
        int u0 = sortedSrc[e + 0];
        int u1 = sortedSrc[e + 1];
        int u2 = sortedSrc[e + 2];
        int u3 = sortedSrc[e + 3];
        float d0 = dinv[u0], d1 = dinv[u1], d2 = dinv[u2], d3 = dinv[u3];
        float4 x0 = X4[(size_t)u0 * 16 + fl];
        float4 x1 = X4[(size_t)u1 * 16 + fl];
        float4 x2 = X4[(size_t)u2 * 16 + fl];
        float4 x3 = X4[(size_t)u3 * 16 + fl];
        ax0 = fmaf(d0, x0.x, ax0); ay0 = fmaf(d0, x0.y, ay0);
        az0 = fmaf(d0, x0.z, az0); aw0 = fmaf(d0, x0.w, aw0);
        ax1 = fmaf(d1, x1.x, ax1); ay1 = fmaf(d1, x1.y, ay1);
        az1 = fmaf(d1, x1.z, az1); aw1 = fmaf(d1, x1.w, aw1);
        ax2 = fmaf(d2, x2.x, ax2); ay2 = fmaf(d2, x2.y, ay2);
        az2 = fmaf(d2, x2.z, az2); aw2 = fmaf(d2, x2.w, aw2);
        ax3 = fmaf(d3, x3.x, ax3); ay3 = fmaf(d3, x3.y, ay3);
        az3 = fmaf(d3, x3.z, az3); aw3 = fmaf(d3, x3.w, aw3);
    }
    for (; e < e1; ++e) {
        int u = sortedSrc[e];
        float d = dinv[u];
        float4 x = X4[(size_t)u * 16 + fl];
        ax0 = fmaf(d, x.x, ax0); ay0 = fmaf(d, x.y, ay0);
        az0 = fmaf(d, x.z, az0); aw0 = fmaf(d, x.w, aw0);
    }
    float ax = (ax0 + ax1) + (ax2 + ax3);
    float ay = (ay0 + ay1) + (ay2 + ay3);
    float az = (az0 + az1) + (az2 + az3);
    float aw = (aw0 + aw1) + (aw2 + aw3);
    float dv = dinv[v];
    float c = dv * dv;
    float4 xs = X4[(size_t)v * 16 + fl];
    float4 o;
    o.x = c * fmaf(dv, xs.x, ax);
    o.y = c * fmaf(dv, xs.y, ay);
    o.z = c * fmaf(dv, xs.z, az);
    o.w = c * fmaf(dv, xs.w, aw);
    Z1s[(size_t)v * 16 + fl] = o;
}

// ---- out[p] = z2 @ M + s*cvec + b2 ----
__global__ void k_out(const int* __restrict__ inp, const float4* __restrict__ Z1s,
                      const float* __restrict__ dinv, const int* __restrict__ rowStart,
                      const int* __restrict__ sortedSrc, const float* __restrict__ M,
                      const float* __restrict__ cvec, const float* __restrict__ b2,
                      float* __restrict__ out) {
    int wid = threadIdx.x >> 6;
    int lane = threadIdx.x & 63;
    int g = lane >> 4, fl = lane & 15;
    int p = blockIdx.x * 4 + wid;
    if (p >= NPOS) return;
    int v = inp[p];
    int e0 = rowStart[v], e1 = rowStart[v + 1];
    float ax0 = 0.f, ay0 = 0.f, az0 = 0.f, aw0 = 0.f, ss0 = 0.f;
    float ax1 = 0.f, ay1 = 0.f, az1 = 0.f, aw1 = 0.f, ss1 = 0.f;
    int e = e0 + g;
    for (; e + 4 < e1; e += 8) {
        int u0 = sortedSrc[e];
        int u1 = sortedSrc[e + 4];
        ss0 += dinv[u0]; ss1 += dinv[u1];
        float4 z0 = Z1s[(size_t)u0 * 16 + fl];
        float4 z1 = Z1s[(size_t)u1 * 16 + fl];
        ax0 += z0.x; ay0 += z0.y; az0 += z0.z; aw0 += z0.w;
        ax1 += z1.x; ay1 += z1.y; az1 += z1.z; aw1 += z1.w;
    }
    if (e < e1) {
        int u = sortedSrc[e];
        ss0 += dinv[u];
        float4 z = Z1s[(size_t)u * 16 + fl];
        ax0 += z.x; ay0 += z.y; az0 += z.z; aw0 += z.w;
    }
    float ax = ax0 + ax1, ay = ay0 + ay1, az = az0 + az1, aw = aw0 + aw1, ss = ss0 + ss1;
    ax += __shfl_xor(ax, 16, 64); ay += __shfl_xor(ay, 16, 64);
    az += __shfl_xor(az, 16, 64); aw += __shfl_xor(aw, 16, 64);
    ss += __shfl_xor(ss, 16, 64);
    ax += __shfl_xor(ax, 32, 64); ay += __shfl_xor(ay, 32, 64);
    az += __shfl_xor(az, 32, 64); aw += __shfl_xor(aw, 32, 64);
    ss += __shfl_xor(ss, 32, 64);
    float dv = dinv[v];
    float4 zs = Z1s[(size_t)v * 16 + fl];
    float z2x = dv * (ax + zs.x);
    float z2y = dv * (ay + zs.y);
    float z2z = dv * (az + zs.z);
    float z2w = dv * (aw + zs.w);
    float s = dv * (ss + dv);
    float o = fmaf(s, cvec[lane], b2[lane]);
    #pragma unroll
    for (int kb = 0; kb < 16; kb++) {
        float a0 = __shfl(z2x, kb, 64);
        float a1 = __shfl(z2y, kb, 64);
        float a2 = __shfl(z2z, kb, 64);
        float a3 = __shfl(z2w, kb, 64);
        o = fmaf(a0, M[(kb * 4 + 0) * 64 + lane], o);
        o = fmaf(a1, M[(kb * 4 + 1) * 64 + lane], o);
        o = fmaf(a2, M[(kb * 4 + 2) * 64 + lane], o);
        o = fmaf(a3, M[(kb * 4 + 3) * 64 + lane], o);
    }
    out[(size_t)p * 64 + lane] = o;
}

extern "C" void kernel_launch(void* const* d_in, const int* in_sizes, int n_in,
                              void* d_out, int out_size, void* d_ws, size_t ws_size,
                              hipStream_t stream) {
    const float* emb = (const float*)d_in[0];
    const float* W1  = (const float*)d_in[1];
    const float* b1  = (const float*)d_in[2];
    const float* W2  = (const float*)d_in[3];
    const float* b2  = (const float*)d_in[4];
    const int*   inp = (const int*)d_in[5];
    // d_in[6] = input_timestamp (unused by the reference)
    const int*   ei  = (const int*)d_in[7];
    const int* srcArr = ei;
    const int* dstArr = ei + NEDGE;
    float* out = (float*)d_out;

    float* ws         = (float*)d_ws;
    float* Z1s        = ws + O_Z1;
    int*   histG      = (int*)ws + O_HIST;
    int*   colTotal   = (int*)ws + O_CTOT;
    int*   bucketStart= (int*)ws + O_BSTART;
    float* dinv       = ws + O_DINV;
    int*   rowStart   = (int*)ws + O_ROWSTART;
    int*   buckPacked = (int*)ws + O_BUCK;     // becomes sortedSrc after kDE
    float* M          = ws + O_M;
    float* cvec       = ws + O_CVEC;

    kA_hist    <<<NBLK,  1024, 0, stream>>>(dstArr, histG);
    kB1_colscan<<<NBUCK, 256,  0, stream>>>(histG, colTotal);
    kB2_scan   <<<1,     256,  0, stream>>>(colTotal, bucketStart);
    kC_scatter <<<NBLK,  1024, 0, stream>>>(srcArr, dstArr, histG, bucketStart, buckPacked);
    kDE        <<<NBUCK, 1024, 0, stream>>>(bucketStart, buckPacked, dinv, rowStart);
    k_smallmat <<<17,    256,  0, stream>>>(W1, b1, W2, M, cvec);
    k_agg      <<<NTOKEN/16, 256, 0, stream>>>((const float4*)emb, dinv, rowStart,
                                               buckPacked, (float4*)Z1s);
    k_out      <<<NPOS/4, 256, 0, stream>>>(inp, (const float4*)Z1s, dinv, rowStart,
                                            buckPacked, M, cvec, b2, out);
}

// Round 6
// 170.506 us; speedup vs baseline: 3.5455x; 1.0244x over previous
//
#include <hip/hip_runtime.h>
#include <hip/hip_bf16.h>

#define NTOKEN 150000
#define NINP   64
#define NEDGE  2400000
#define NPOS   (64*200)

#define NPB    256            // nodes per bucket (bucket = dst >> 8)
#define NBUCK  586            // ceil(NTOKEN / NPB)
#define EPB    8192           // edges per block in kA/kC
#define NBLK   293            // ceil(NEDGE / EPB)
#define CAP    6144           // LDS edge capacity per bucket (avg 4096, sigma~64)

// word (4-byte) offsets into workspace (total ~50.4 MiB)
#define O_Z1       0              // f32 [150000*64]; written in k_agg (after histG dead)
#define O_HIST     0              // i32 [NBLK*NBUCK=171698]; last read in kC
#define O_CTOT     9600000        // i32 [586]
#define O_BSTART   9600640        // i32 [587]
#define O_DINV     9601280        // f32 [150000]
#define O_ROWSTART 9751296        // i32 [150001]
#define O_BUCK     9901312        // i32 [2400000] packed (src<<8|local); sorted in place by kDE
#define O_M        12301312       // f32 [4096]  (W1@W2)
#define O_CVEC     12305408       // f32 [64]    (b1@W2)

// ---- Pass A: per-block bucket histogram (LDS atomics only), int4 edge reads ----
__global__ void kA_hist(const int4* __restrict__ dst4, int* __restrict__ histG) {
    __shared__ int h[NBUCK];
    int tid = threadIdx.x;
    for (int i = tid; i < NBUCK; i += 1024) h[i] = 0;
    __syncthreads();
    int base4 = blockIdx.x * (EPB / 4);
    #pragma unroll
    for (int i = 0; i < EPB / 4096; i++) {
        int idx = base4 + i * 1024 + tid;
        if (idx < NEDGE / 4) {
            int4 d = dst4[idx];
            atomicAdd(&h[d.x >> 8], 1);
            atomicAdd(&h[d.y >> 8], 1);
            atomicAdd(&h[d.z >> 8], 1);
            atomicAdd(&h[d.w >> 8], 1);
        }
    }
    __syncthreads();
    for (int i = tid; i < NBUCK; i += 1024) histG[blockIdx.x * NBUCK + i] = h[i];
}

// ---- Pass B1: per-bucket column exclusive scan over blocks; one block per bucket ----
__global__ void kB1_colscan(int* __restrict__ histG, int* __restrict__ colTotal) {
    __shared__ int sd[256];
    int t = threadIdx.x, b = blockIdx.x;
    int i0 = 2 * t, i1 = 2 * t + 1;
    int v0 = (i0 < NBLK) ? histG[i0 * NBUCK + b] : 0;
    int v1 = (i1 < NBLK) ? histG[i1 * NBUCK + b] : 0;
    int tsum = v0 + v1;
    sd[t] = tsum;
    __syncthreads();
    for (int off = 1; off < 256; off <<= 1) {
        int x = (t >= off) ? sd[t - off] : 0;
        __syncthreads();
        sd[t] += x;
        __syncthreads();
    }
    int excl = sd[t] - tsum;
    if (i0 < NBLK) histG[i0 * NBUCK + b] = excl;
    if (i1 < NBLK) histG[i1 * NBUCK + b] = excl + v0;
    if (t == 255) colTotal[b] = sd[255];
}

// ---- Pass B2 (+smallmat fused): block 0 = bucket scan; blocks 1..16 = M; block 17 = cvec ----
__global__ void kB2s(const int* __restrict__ colTotal, int* __restrict__ bucketStart,
                     const float* __restrict__ W1, const float* __restrict__ b1,
                     const float* __restrict__ W2,
                     float* __restrict__ M, float* __restrict__ cvec) {
    int bb = blockIdx.x;
    int t = threadIdx.x;
    if (bb == 0) {
        __shared__ int sd[256];
        int i0 = t * 3, i1 = t * 3 + 1, i2 = t * 3 + 2;
        int v0 = (i0 < NBUCK) ? colTotal[i0] : 0;
        int v1 = (i1 < NBUCK) ? colTotal[i1] : 0;
        int v2 = (i2 < NBUCK) ? colTotal[i2] : 0;
        int tsum = v0 + v1 + v2;
        sd[t] = tsum;
        __syncthreads();
        for (int off = 1; off < 256; off <<= 1) {
            int x = (t >= off) ? sd[t - off] : 0;
            __syncthreads();
            sd[t] += x;
            __syncthreads();
        }
        int excl = sd[t] - tsum;
        if (i0 < NBUCK) bucketStart[i0] = excl;
        if (i1 < NBUCK) bucketStart[i1] = excl + v0;
        if (i2 < NBUCK) bucketStart[i2] = excl + v0 + v1;
        if (t == 255) bucketStart[NBUCK] = NEDGE;
    } else if (bb <= 16) {
        int o = (bb - 1) * 256 + t;
        int i = o >> 6, j = o & 63;
        float s = 0.f;
        #pragma unroll 4
        for (int k = 0; k < 128; k++) s = fmaf(W1[i * 128 + k], W2[k * 64 + j], s);
        M[o] = s;
    } else if (t < 64) {
        float s = 0.f;
        #pragma unroll 4
        for (int k = 0; k < 128; k++) s = fmaf(b1[k], W2[k * 64 + t], s);
        cvec[t] = s;
    }
}

// ---- Pass C: scatter edges into bucket regions (LDS cursors), int4 edge reads ----
__global__ void kC_scatter(const int4* __restrict__ src4, const int4* __restrict__ dst4,
                           const int* __restrict__ histG, const int* __restrict__ bucketStart,
                           int* __restrict__ bucketPacked) {
    __shared__ int cur[NBUCK];
    int tid = threadIdx.x;
    for (int i = tid; i < NBUCK; i += 1024)
        cur[i] = histG[blockIdx.x * NBUCK + i] + bucketStart[i];
    __syncthreads();
    int base4 = blockIdx.x * (EPB / 4);
    #pragma unroll
    for (int i = 0; i < EPB / 4096; i++) {
        int idx = base4 + i * 1024 + tid;
        if (idx < NEDGE / 4) {
            int4 s = src4[idx];
            int4 d = dst4[idx];
            int p0 = atomicAdd(&cur[d.x >> 8], 1);
            bucketPacked[p0] = (s.x << 8) | (d.x & 255);
            int p1 = atomicAdd(&cur[d.y >> 8], 1);
            bucketPacked[p1] = (s.y << 8) | (d.y & 255);
            int p2 = atomicAdd(&cur[d.z >> 8], 1);
            bucketPacked[p2] = (s.z << 8) | (d.z & 255);
            int p3 = atomicAdd(&cur[d.w >> 8], 1);
            bucketPacked[p3] = (s.w << 8) | (d.w & 255);
        }
    }
}

// ---- Pass DE: per-bucket count+scan -> dinv/rowStart; LDS sort; CSR dump ----
__global__ void kDE(const int* __restrict__ bucketStart,
                    int* __restrict__ bucketPacked /* in: packed; out: sortedSrc */,
                    float* __restrict__ dinv, int* __restrict__ rowStart) {
    __shared__ int raw[CAP];
    __shared__ int srt[CAP];
    __shared__ int cnt[NPB];
    __shared__ int sd[NPB];
    int t = threadIdx.x, b = blockIdx.x;
    int e0 = bucketStart[b], e1 = bucketStart[b + 1];
    int nE = e1 - e0;
    int nEc = (nE < CAP) ? nE : CAP;
    if (t < NPB) cnt[t] = 0;
    __syncthreads();
    for (int i = t; i < nEc; i += 1024) {
        int p = bucketPacked[e0 + i];
        raw[i] = p;
        atomicAdd(&cnt[p & 255], 1);
    }
    __syncthreads();
    int c = 0;
    if (t < NPB) { c = cnt[t]; sd[t] = c; }
    __syncthreads();
    for (int off = 1; off < 256; off <<= 1) {
        int x = 0;
        if (t < NPB && t >= off) x = sd[t - off];
        __syncthreads();
        if (t < NPB) sd[t] += x;
        __syncthreads();
    }
    if (t < NPB) {
        int excl = sd[t] - c;
        cnt[t] = excl;                    // becomes cursor
        int node = b * NPB + t;
        if (node < NTOKEN) {
            dinv[node] = rsqrtf((float)c + 1.0f);
            rowStart[node] = e0 + excl;
        }
        if (b == NBUCK - 1 && t == 0) rowStart[NTOKEN] = NEDGE;
    }
    __syncthreads();
    for (int i = t; i < nEc; i += 1024) {
        int p = raw[i];
        int pos = atomicAdd(&cnt[p & 255], 1);
        if (pos < CAP) srt[pos] = p >> 8;
    }
    __syncthreads();
    for (int i = t; i < nEc; i += 1024) bucketPacked[e0 + i] = srt[i];
}

// ---- Z1s[v] = dv^2*( sum_u dinv[u]*X[u] + dv*X[v] ); 16-lane group/node, masked unroll 8 ----
__global__ void k_agg(const float4* __restrict__ X4, const float* __restrict__ dinv,
                      const int* __restrict__ rowStart, const int* __restrict__ sortedSrc,
                      float4* __restrict__ Z1s) {
    int g = threadIdx.x >> 4;           // 16 groups per block
    int fl = threadIdx.x & 15;
    int v = blockIdx.x * 16 + g;        // grid*16 == NTOKEN exactly
    int e0 = rowStart[v], e1 = rowStart[v + 1];
    float dv = dinv[v];
    float4 xs = X4[(size_t)v * 16 + fl];
    float4 a0 = {0.f,0.f,0.f,0.f}, a1 = {0.f,0.f,0.f,0.f};
    float4 a2 = {0.f,0.f,0.f,0.f}, a3 = {0.f,0.f,0.f,0.f};
    for (int e = e0; e < e1; e += 8) {
        int m1 = e + 1 < e1, m2 = e + 2 < e1, m3 = e + 3 < e1;
        int m4 = e + 4 < e1, m5 = e + 5 < e1, m6 = e + 6 < e1, m7 = e + 7 < e1;
        int u0 = sortedSrc[e];
        int u1 = sortedSrc[m1 ? e + 1 : e];
        int u2 = sortedSrc[m2 ? e + 2 : e];
        int u3 = sortedSrc[m3 ? e + 3 : e];
        int u4 = sortedSrc[m4 ? e + 4 : e];
        int u5 = sortedSrc[m5 ? e + 5 : e];
        int u6 = sortedSrc[m6 ? e + 6 : e];
        int u7 = sortedSrc[m7 ? e + 7 : e];
        float d0 = dinv[u0];
        float d1 = m1 ? dinv[u1] : 0.f;
        float d2 = m2 ? dinv[u2] : 0.f;
        float d3 = m3 ? dinv[u3] : 0.f;
        float d4 = m4 ? dinv[u4] : 0.f;
        float d5 = m5 ? dinv[u5] : 0.f;
        float d6 = m6 ? dinv[u6] : 0.f;
        float d7 = m7 ? dinv[u7] : 0.f;
        float4 x0 = X4[(size_t)u0 * 16 + fl];
        float4 x1 = X4[(size_t)u1 * 16 + fl];
        float4 x2 = X4[(size_t)u2 * 16 + fl];
        float4 x3 = X4[(size_t)u3 * 16 + fl];
        float4 x4 = X4[(size_t)u4 * 16 + fl];
        float4 x5 = X4[(size_t)u5 * 16 + fl];
        float4 x6 = X4[(size_t)u6 * 16 + fl];
        float4 x7 = X4[(size_t)u7 * 16 + fl];
        a0.x = fmaf(d0, x0.x, a0.x); a0.y = fmaf(d0, x0.y, a0.y);
        a0.z = fmaf(d0, x0.z, a0.z); a0.w = fmaf(d0, x0.w, a0.w);
        a1.x = fmaf(d1, x1.x, a1.x); a1.y = fmaf(d1, x1.y, a1.y);
        a1.z = fmaf(d1, x1.z, a1.z); a1.w = fmaf(d1, x1.w, a1.w);
        a2.x = fmaf(d2, x2.x, a2.x); a2.y = fmaf(d2, x2.y, a2.y);
        a2.z = fmaf(d2, x2.z, a2.z); a2.w = fmaf(d2, x2.w, a2.w);
        a3.x = fmaf(d3, x3.x, a3.x); a3.y = fmaf(d3, x3.y, a3.y);
        a3.z = fmaf(d3, x3.z, a3.z); a3.w = fmaf(d3, x3.w, a3.w);
        a0.x = fmaf(d4, x4.x, a0.x); a0.y = fmaf(d4, x4.y, a0.y);
        a0.z = fmaf(d4, x4.z, a0.z); a0.w = fmaf(d4, x4.w, a0.w);
        a1.x = fmaf(d5, x5.x, a1.x); a1.y = fmaf(d5, x5.y, a1.y);
        a1.z = fmaf(d5, x5.z, a1.z); a1.w = fmaf(d5, x5.w, a1.w);
        a2.x = fmaf(d6, x6.x, a2.x); a2.y = fmaf(d6, x6.y, a2.y);
        a2.z = fmaf(d6, x6.z, a2.z); a2.w = fmaf(d6, x6.w, a2.w);
        a3.x = fmaf(d7, x7.x, a3.x); a3.y = fmaf(d7, x7.y, a3.y);
        a3.z = fmaf(d7, x7.z, a3.z); a3.w = fmaf(d7, x7.w, a3.w);
    }
    float ax = (a0.x + a1.x) + (a2.x + a3.x);
    float ay = (a0.y + a1.y) + (a2.y + a3.y);
    float az = (a0.z + a1.z) + (a2.z + a3.z);
    float aw = (a0.w + a1.w) + (a2.w + a3.w);
    float c = dv * dv;
    float4 o;
    o.x = c * fmaf(dv, xs.x, ax);
    o.y = c * fmaf(dv, xs.y, ay);
    o.z = c * fmaf(dv, xs.z, az);
    o.w = c * fmaf(dv, xs.w, aw);
    Z1s[(size_t)v * 16 + fl] = o;
}

// ---- out[p] = z2 @ M + s*cvec + b2 ----
__global__ void k_out(const int* __restrict__ inp, const float4* __restrict__ Z1s,
                      const float* __restrict__ dinv, const int* __restrict__ rowStart,
                      const int* __restrict__ sortedSrc, const float* __restrict__ M,
                      const float* __restrict__ cvec, const float* __restrict__ b2,
                      float* __restrict__ out) {
    int wid = threadIdx.x >> 6;
    int lane = threadIdx.x & 63;
    int g = lane >> 4, fl = lane & 15;
    int p = blockIdx.x * 4 + wid;
    if (p >= NPOS) return;
    int v = inp[p];
    int e0 = rowStart[v], e1 = rowStart[v + 1];
    float ax0 = 0.f, ay0 = 0.f, az0 = 0.f, aw0 = 0.f, ss0 = 0.f;
    float ax1 = 0.f, ay1 = 0.f, az1 = 0.f, aw1 = 0.f, ss1 = 0.f;
    int e = e0 + g;
    for (; e + 4 < e1; e += 8) {
        int u0 = sortedSrc[e];
        int u1 = sortedSrc[e + 4];
        ss0 += dinv[u0]; ss1 += dinv[u1];
        float4 z0 = Z1s[(size_t)u0 * 16 + fl];
        float4 z1 = Z1s[(size_t)u1 * 16 + fl];
        ax0 += z0.x; ay0 += z0.y; az0 += z0.z; aw0 += z0.w;
        ax1 += z1.x; ay1 += z1.y; az1 += z1.z; aw1 += z1.w;
    }
    if (e < e1) {
        int u = sortedSrc[e];
        ss0 += dinv[u];
        float4 z = Z1s[(size_t)u * 16 + fl];
        ax0 += z.x; ay0 += z.y; az0 += z.z; aw0 += z.w;
    }
    float ax = ax0 + ax1, ay = ay0 + ay1, az = az0 + az1, aw = aw0 + aw1, ss = ss0 + ss1;
    ax += __shfl_xor(ax, 16, 64); ay += __shfl_xor(ay, 16, 64);
    az += __shfl_xor(az, 16, 64); aw += __shfl_xor(aw, 16, 64);
    ss += __shfl_xor(ss, 16, 64);
    ax += __shfl_xor(ax, 32, 64); ay += __shfl_xor(ay, 32, 64);
    az += __shfl_xor(az, 32, 64); aw += __shfl_xor(aw, 32, 64);
    ss += __shfl_xor(ss, 32, 64);
    float dv = dinv[v];
    float4 zs = Z1s[(size_t)v * 16 + fl];
    float z2x = dv * (ax + zs.x);
    float z2y = dv * (ay + zs.y);
    float z2z = dv * (az + zs.z);
    float z2w = dv * (aw + zs.w);
    float s = dv * (ss + dv);
    float o = fmaf(s, cvec[lane], b2[lane]);
    #pragma unroll
    for (int kb = 0; kb < 16; kb++) {
        float a0 = __shfl(z2x, kb, 64);
        float a1 = __shfl(z2y, kb, 64);
        float a2 = __shfl(z2z, kb, 64);
        float a3 = __shfl(z2w, kb, 64);
        o = fmaf(a0, M[(kb * 4 + 0) * 64 + lane], o);
        o = fmaf(a1, M[(kb * 4 + 1) * 64 + lane], o);
        o = fmaf(a2, M[(kb * 4 + 2) * 64 + lane], o);
        o = fmaf(a3, M[(kb * 4 + 3) * 64 + lane], o);
    }
    out[(size_t)p * 64 + lane] = o;
}

extern "C" void kernel_launch(void* const* d_in, const int* in_sizes, int n_in,
                              void* d_out, int out_size, void* d_ws, size_t ws_size,
                              hipStream_t stream) {
    const float* emb = (const float*)d_in[0];
    const float* W1  = (const float*)d_in[1];
    const float* b1  = (const float*)d_in[2];
    const float* W2  = (const float*)d_in[3];
    const float* b2  = (const float*)d_in[4];
    const int*   inp = (const int*)d_in[5];
    // d_in[6] = input_timestamp (unused by the reference)
    const int*   ei  = (const int*)d_in[7];
    const int* srcArr = ei;
    const int* dstArr = ei + NEDGE;
    float* out = (float*)d_out;

    float* ws         = (float*)d_ws;
    float* Z1s        = ws + O_Z1;
    int*   histG      = (int*)ws + O_HIST;
    int*   colTotal   = (int*)ws + O_CTOT;
    int*   bucketStart= (int*)ws + O_BSTART;
    float* dinv       = ws + O_DINV;
    int*   rowStart   = (int*)ws + O_ROWSTART;
    int*   buckPacked = (int*)ws + O_BUCK;     // becomes sortedSrc after kDE
    float* M          = ws + O_M;
    float* cvec       = ws + O_CVEC;

    kA_hist    <<<NBLK,  1024, 0, stream>>>((const int4*)dstArr, histG);
    kB1_colscan<<<NBUCK, 256,  0, stream>>>(histG, colTotal);
    kB2s       <<<18,    256,  0, stream>>>(colTotal, bucketStart, W1, b1, W2, M, cvec);
    kC_scatter <<<NBLK,  1024, 0, stream>>>((const int4*)srcArr, (const int4*)dstArr,
                                            histG, bucketStart, buckPacked);
    kDE        <<<NBUCK, 1024, 0, stream>>>(bucketStart, buckPacked, dinv, rowStart);
    k_agg      <<<NTOKEN/16, 256, 0, stream>>>((const float4*)emb, dinv, rowStart,
                                               buckPacked, (float4*)Z1s);
    k_out      <<<NPOS/4, 256, 0, stream>>>(inp, (const float4*)Z1s, dinv, rowStart,
                                            buckPacked, M, cvec, b2, out);
}